// Round 5
// baseline (246.676 us; speedup 1.0000x reference)
//
#include <hip/hip_runtime.h>

#define DD 256
#define HH 512
#define BB 128
#define TS 4096   // floats per tape block (16 KB)

#define WAITVM(N) asm volatile("s_waitcnt vmcnt(" #N ")" ::: "memory")

__device__ __forceinline__ float elu_f(float x) {
    return x > 0.f ? x : (__expf(x) - 1.f);
}
__device__ __forceinline__ float rlf(float v, int l) {
    return __uint_as_float(__builtin_amdgcn_readlane(__float_as_uint(v), (unsigned)l));
}
__device__ __forceinline__ float f4c(const float4& v, int r) {
    return r == 0 ? v.x : r == 1 ? v.y : r == 2 ? v.z : v.w;
}

// Unit slot map: lane L, A-reg r (0..3) <-> h = L+64r  [exception (63,3) -> h=510]
//                lane L, B-reg 4+r     <-> h = 255+L+64r [exception (63,3) -> h=511]
__device__ __forceinline__ int pmap(int h) {
    if (h == 510) return 255;
    if (h == 511) return 511;
    return (h < 255) ? (4 * (h & 63) + (h >> 6))
                     : (256 + 4 * ((h - 255) & 63) + ((h - 255) >> 6));
}
__device__ __forceinline__ int p4map(int j) {      // j in [0,256): column map
    return 4 * (j & 63) + (j >> 6);
}
__device__ __forceinline__ int w1base(int hp) {    // m at +0, l at +512
    return (hp <= 254) ? hp * TS
         : (hp <= 509) ? (hp - 255) * TS + 1024
         : 255 * TS + ((hp == 510) ? 0 : 1024);
}
__device__ __forceinline__ int wobase(int hp) {    // m at +0, l at +256
    return (hp <= 254) ? hp * TS + 3072
         : (hp <= 509) ? (hp - 255) * TS + 3584
         : 255 * TS + ((hp == 510) ? 2048 : 2560);
}

// Tape block i (4096 floats), rows lane-packed [pos = p(h) or p4(j)]:
//  [0/512]    W1T[i]     m/l     [1024/1536] W1T[i+255] m/l
//  [2048/2560] W0T[i]    m/l     [3072/3328] WoT[i]     m/l (256)
//  [3584/3840] WoT[i+255] m/l
// Block 255 = appendix: W1T[510] m/l @0/512, W1T[511] m/l @1024/1536,
//  WoT[510] m/l @2048/2304, WoT[511] m/l @2560/2816.  [3072..4095 unused]
__global__ __launch_bounds__(256) void prep(
    const float* __restrict__ w0m_, const float* __restrict__ w0l_,
    const float* __restrict__ w1m_, const float* __restrict__ w1l_,
    const float* __restrict__ wom_, const float* __restrict__ wol_,
    float* __restrict__ tape)
{
    __shared__ float tm[32][33], tl[32][33];
    const int tx = threadIdx.x & 31, ty = threadIdx.x >> 5;
    const unsigned b = blockIdx.x;

    if (b < 256) {                              // W1: 16 h-tiles x 16 hp-tiles
        const int h0 = (int)(b >> 4) << 5, hp0 = (int)(b & 15) << 5;
        #pragma unroll
        for (int j = 0; j < 4; ++j) {
            int r = ty + 8 * j;
            tm[r][tx] = w1m_[(h0 + r) * HH + hp0 + tx];
            tl[r][tx] = w1l_[(h0 + r) * HH + hp0 + tx];
        }
        __syncthreads();
        #pragma unroll
        for (int j = 0; j < 4; ++j) {
            int hp = hp0 + ty + 8 * j;
            int h  = h0 + tx;
            int dh_h = (h <= 254) ? h + 1 : (h <= 509 ? h - 254 : h - 509);
            int dh_p = (hp <= 254) ? hp + 1 : (hp <= 509 ? hp - 254 : hp - 509);
            float mask = (dh_h >= dh_p) ? 1.f : 0.f;
            int base = w1base(hp), p = pmap(h);
            tape[base + p]       = mask * tm[tx][ty + 8 * j];
            tape[base + 512 + p] = mask * tl[tx][ty + 8 * j];
        }
    } else if (b < 384) {                       // W0: 16 h-tiles x 8 i-tiles
        const int b2 = (int)b - 256;
        const int h0 = (b2 >> 3) << 5, i0 = (b2 & 7) << 5;
        #pragma unroll
        for (int j = 0; j < 4; ++j) {
            int r = ty + 8 * j;
            tm[r][tx] = w0m_[(h0 + r) * DD + i0 + tx];
            tl[r][tx] = w0l_[(h0 + r) * DD + i0 + tx];
        }
        __syncthreads();
        #pragma unroll
        for (int j = 0; j < 4; ++j) {
            int i = i0 + ty + 8 * j;
            int h = h0 + tx;
            int p = pmap(h);
            tape[i * TS + 2048 + p] = tm[tx][ty + 8 * j];
            tape[i * TS + 2560 + p] = tl[tx][ty + 8 * j];
        }
    } else {                                    // Wo: 8 j-tiles x 16 hp-tiles
        const int b3 = (int)b - 384;
        const int j0 = (b3 >> 4) << 5, hp0 = (b3 & 15) << 5;
        #pragma unroll
        for (int j = 0; j < 4; ++j) {
            int r = ty + 8 * j;
            tm[r][tx] = wom_[(j0 + r) * HH + hp0 + tx];
            tl[r][tx] = wol_[(j0 + r) * HH + hp0 + tx];
        }
        __syncthreads();
        #pragma unroll
        for (int j = 0; j < 4; ++j) {
            int hp = hp0 + ty + 8 * j;
            int jj = j0 + tx;
            int base = wobase(hp), p = p4map(jj);
            tape[base + p]       = tm[tx][ty + 8 * j];
            tape[base + 256 + p] = tl[tx][ty + 8 * j];
        }
    }
}

// ================================ main =====================================
struct WSet { float4 w[16]; };

// stage one 16 KB group into an LDS ring slot via direct-to-LDS DMA
// (no destination VGPRs -> zero register pressure; counted by vmcnt).
__device__ __forceinline__ void stage16(const float* g, float* l, int lane) {
    #pragma unroll
    for (int k = 0; k < 16; ++k) {
        __builtin_amdgcn_global_load_lds(
            (const __attribute__((address_space(1))) void*)(g + 256 * k + 4 * lane),
            (__attribute__((address_space(3))) void*)(l + 256 * k),
            16, 0, 0);
    }
}

// LDS -> registers in USE order: layer-0 weights (w8-11) first, then layer-1
// in consumption order (w0,w4,w1,w5,w2,w6,w3,w7), then output (w12,w14,w13,w15).
// LDS returns in issue order, so layer-0 unblocks after 4 returns.
__device__ __forceinline__ void rd_use(WSet& S, const float* b, int lane) {
    const float4* p = (const float4*)b;
    const int ord[16] = {8, 9, 10, 11, 0, 4, 1, 5, 2, 6, 3, 7, 12, 14, 13, 15};
    #pragma unroll
    for (int k = 0; k < 16; ++k) S.w[ord[k]] = p[64 * ord[k] + lane];
}

// scalar chain for step tn (runs at END of previous step, off the read path):
// mu/ls from freshly updated R, ls_sum accumulate, v = (x - mu)/(exp(ls)+eps)
template<int QN>
__device__ __forceinline__ float nextV(
    int tn, const float (&Rm)[4], const float (&Rl)[4],
    const float (&xv)[4], const float (&bmv)[4], const float (&blv)[4],
    float& ls_sum)
{
    float mu = rlf(Rm[QN], tn) + rlf(bmv[QN], tn);
    float ls = 0.5f * (rlf(Rl[QN], tn) + rlf(blv[QN], tn));
    ls_sum += ls;
    return __fdividef(rlf(xv[QN], tn) - mu, __expf(ls) + 1e-12f);
}

// w[0..3]=W1T[i] mA,mB,lA,lB  w[4..7]=W1T[i+255] mA,mB,lA,lB
// w[8..11]=W0T[i] mA,mB,lA,lB  w[12..15]=WoT[i]m, WoT[i]l, WoT[i+255]m, WoT[i+255]l
template<int Q, int EX>
__device__ __forceinline__ void stepC_v(
    int t, int lane, float v, const WSet& S,
    float (&a0m)[8], float (&a0l)[8], float (&a1m)[8], float (&a1l)[8],
    float (&Rm)[4], float (&Rl)[4], float (&yv)[4],
    const float4& exmA, const float4& exmB, const float4& exlA, const float4& exlB,
    const float4& exwm, const float4& exwl)
{
    yv[Q] = (lane == t) ? v : yv[Q];

    #pragma unroll
    for (int r = Q; r < 4; ++r) {
        a0m[r]     += v * f4c(S.w[8], r);
        a0m[4 + r] += v * f4c(S.w[9], r);
        a0l[r]     += v * f4c(S.w[10], r);
        a0l[4 + r] += v * f4c(S.w[11], r);
    }

    float p0m = elu_f(rlf(a0m[Q], t)),     p0l = elu_f(rlf(a0l[Q], t));
    float p1m = elu_f(rlf(a0m[4 + Q], t)), p1l = elu_f(rlf(a0l[4 + Q], t));
    float p2m = 0.f, p2l = 0.f;
    if (EX) {
        p2m = elu_f(rlf(a0m[EX == 1 ? 3 : 7], 63));
        p2l = elu_f(rlf(a0l[EX == 1 ? 3 : 7], 63));
    }

    #pragma unroll
    for (int r = Q; r < 4; ++r) {
        a1m[r]     += f4c(S.w[0], r) * p0m + f4c(S.w[4], r) * p1m;
        a1m[4 + r] += f4c(S.w[1], r) * p0m + f4c(S.w[5], r) * p1m;
        a1l[r]     += f4c(S.w[2], r) * p0l + f4c(S.w[6], r) * p1l;
        a1l[4 + r] += f4c(S.w[3], r) * p0l + f4c(S.w[7], r) * p1l;
    }
    if (EX) {
        #pragma unroll
        for (int r = 0; r < 4; ++r) {
            a1m[r]     += f4c(exmA, r) * p2m;
            a1m[4 + r] += f4c(exmB, r) * p2m;
            a1l[r]     += f4c(exlA, r) * p2l;
            a1l[4 + r] += f4c(exlB, r) * p2l;
        }
    }

    float q0m = elu_f(rlf(a1m[Q], t)),     q0l = elu_f(rlf(a1l[Q], t));
    float q1m = elu_f(rlf(a1m[4 + Q], t)), q1l = elu_f(rlf(a1l[4 + Q], t));
    float q2m = 0.f, q2l = 0.f;
    if (EX) {
        q2m = elu_f(rlf(a1m[EX == 1 ? 3 : 7], 63));
        q2l = elu_f(rlf(a1l[EX == 1 ? 3 : 7], 63));
    }

    #pragma unroll
    for (int r = Q; r < 4; ++r) {
        Rm[r] += f4c(S.w[12], r) * q0m + f4c(S.w[14], r) * q1m;
        Rl[r] += f4c(S.w[13], r) * q0l + f4c(S.w[15], r) * q1l;
    }
    if (EX) {
        #pragma unroll
        for (int r = 0; r < 4; ++r) {
            Rm[r] += f4c(exwm, r) * q2m;
            Rl[r] += f4c(exwl, r) * q2l;
        }
    }
}

// Single wave, no barriers.  4-slot LDS ring fed by the consumer's own
// global_load_lds, 3 steps ahead.  Per step: WAITVM(32) (slot t resident;
// {t+1,t+2,t+3} stay in flight), use-ordered ds_reads, issue stage(t+3),
// compute with precomputed v, then run the scalar chain for t+1.
__global__ __launch_bounds__(64, 1) void made_main(
    const float* __restrict__ x,
    const float* __restrict__ mu_b0, const float* __restrict__ mu_b1,
    const float* __restrict__ mu_bo,
    const float* __restrict__ lv_b0, const float* __restrict__ lv_b1,
    const float* __restrict__ lv_bo,
    const float* __restrict__ tape,
    float* __restrict__ out)
{
    __shared__ __align__(16) float buf[4][TS];
    const int row = blockIdx.x;
    const int lane = threadIdx.x;

    float a0m[8], a0l[8], a1m[8], a1l[8], Rm[4], Rl[4], yv[4];
    float xv[4], bmv[4], blv[4];
    #pragma unroll
    for (int r = 0; r < 4; ++r) {
        a0m[r]     = mu_b0[lane + 64 * r];
        a0m[4 + r] = mu_b0[255 + lane + 64 * r];
        a0l[r]     = lv_b0[lane + 64 * r];
        a0l[4 + r] = lv_b0[255 + lane + 64 * r];
        a1m[r]     = mu_b1[lane + 64 * r];
        a1m[4 + r] = mu_b1[255 + lane + 64 * r];
        a1l[r]     = lv_b1[lane + 64 * r];
        a1l[4 + r] = lv_b1[255 + lane + 64 * r];
        Rm[r] = 0.f; Rl[r] = 0.f; yv[r] = 0.f;
        xv[r]  = x[row * DD + 64 * r + lane];
        bmv[r] = mu_bo[64 * r + lane];
        blv[r] = lv_bo[64 * r + lane];
    }
    if (lane == 63) {   // (63,3) slots host h=510 (A) and h=511 (B)
        a0m[3] = mu_b0[510]; a0m[7] = mu_b0[511];
        a0l[3] = lv_b0[510]; a0l[7] = lv_b0[511];
        a1m[3] = mu_b1[510]; a1m[7] = mu_b1[511];
        a1l[3] = lv_b1[510]; a1l[7] = lv_b1[511];
    }

    // appendix preloads (dead after steps 0/1)
    const float4* a4 = (const float4*)(tape + 255 * TS);
    float4 e510mA = a4[lane],       e510mB = a4[64 + lane];
    float4 e510lA = a4[128 + lane], e510lB = a4[192 + lane];
    float4 e511mA = a4[256 + lane], e511mB = a4[320 + lane];
    float4 e511lA = a4[384 + lane], e511lB = a4[448 + lane];
    float4 wo510m = a4[512 + lane], wo510l = a4[576 + lane];
    float4 wo511m = a4[640 + lane], wo511l = a4[704 + lane];

    const float4 d4 = make_float4(0.f, 0.f, 0.f, 0.f);

    // prime the ring: slots 0,1,2 in flight (48 VMEM ops, + appendix above)
    stage16(tape + 0 * TS, &buf[0][0], lane);
    stage16(tape + 1 * TS, &buf[1][0], lane);
    stage16(tape + 2 * TS, &buf[2][0], lane);

    float ls_sum = 0.f;
    WSet S;

    // step-0 scalar chain (R = 0): identical ops to the original step 0
    float v = nextV<0>(0, Rm, Rl, xv, bmv, blv, ls_sum);

    // ---- t = 0 (extra h=510), slot 0 ----
    WAITVM(32);
    rd_use(S, &buf[0][0], lane);
    stage16(tape + 3 * TS, &buf[3][0], lane);
    stepC_v<0, 1>(0, lane, v, S, a0m, a0l, a1m, a1l, Rm, Rl, yv,
                  e510mA, e510mB, e510lA, e510lB, wo510m, wo510l);
    v = nextV<0>(1, Rm, Rl, xv, bmv, blv, ls_sum);

    // ---- t = 1 (extra h=511), slot 1 ----
    WAITVM(32);
    rd_use(S, &buf[1][0], lane);
    stage16(tape + 4 * TS, &buf[0][0], lane);
    stepC_v<0, 2>(1, lane, v, S, a0m, a0l, a1m, a1l, Rm, Rl, yv,
                  e511mA, e511mB, e511lA, e511lB, wo511m, wo511l);
    v = nextV<0>(2, Rm, Rl, xv, bmv, blv, ls_sum);

#define SSTEP(Q, tt, QN, tn)                                                  \
    {                                                                         \
        WAITVM(32);                                                           \
        rd_use(S, &buf[(tt) & 3][0], lane);                                   \
        if ((tt) + 3 < 255)                                                   \
            stage16(tape + (size_t)((tt) + 3) * TS,                           \
                    &buf[((tt) + 3) & 3][0], lane);                           \
        stepC_v<Q, 0>((tt) - 64 * (Q), lane, v, S, a0m, a0l, a1m, a1l,        \
                      Rm, Rl, yv, d4, d4, d4, d4, d4, d4);                    \
        v = nextV<QN>((tn), Rm, Rl, xv, bmv, blv, ls_sum);                    \
    }

    // ---- Q0: t = 2..63 ----
    #pragma unroll 1
    for (int t = 2; t < 63; ++t) SSTEP(0, t, 0, t + 1)
    SSTEP(0, 63, 1, 0)

    // ---- Q1: t = 64..127 ----
    #pragma unroll 1
    for (int t = 64; t < 127; ++t) SSTEP(1, t, 1, t - 63)
    SSTEP(1, 127, 2, 0)

    // ---- Q2: t = 128..191 ----
    #pragma unroll 1
    for (int t = 128; t < 191; ++t) SSTEP(2, t, 2, t - 127)
    SSTEP(2, 191, 3, 0)

    // ---- Q3: t = 192..252 (stage guard stops issuing at t=251) ----
    #pragma unroll 1
    for (int t = 192; t < 252; ++t) SSTEP(3, t, 3, t - 191)
    SSTEP(3, 252, 3, 61)            // entry outstanding {252,253,254}=48 -> ok

    // ---- t = 253 (outstanding {253,254}=32 -> counted wait 16) ----
    {
        WAITVM(16);
        rd_use(S, &buf[253 & 3][0], lane);
        stepC_v<3, 0>(61, lane, v, S, a0m, a0l, a1m, a1l, Rm, Rl, yv,
                      d4, d4, d4, d4, d4, d4);
        v = nextV<3>(62, Rm, Rl, xv, bmv, blv, ls_sum);
    }
    // ---- t = 254 ----
    {
        WAITVM(0);
        rd_use(S, &buf[254 & 3][0], lane);
        stepC_v<3, 0>(62, lane, v, S, a0m, a0l, a1m, a1l, Rm, Rl, yv,
                      d4, d4, d4, d4, d4, d4);
        v = nextV<3>(63, Rm, Rl, xv, bmv, blv, ls_sum);   // v_255, ls_255 added
    }
#undef SSTEP

    // ---- step 255: output only ----
    yv[3] = (lane == 63) ? v : yv[3];

    #pragma unroll
    for (int r = 0; r < 4; ++r) out[row * DD + 64 * r + lane] = yv[r];
    if (lane == 0) out[BB * DD + row] = ls_sum;
}

extern "C" void kernel_launch(void* const* d_in, const int* in_sizes, int n_in,
                              void* d_out, int out_size, void* d_ws, size_t ws_size,
                              hipStream_t stream) {
    const float* x     = (const float*)d_in[0];
    const float* mu_W0 = (const float*)d_in[1];
    const float* mu_b0 = (const float*)d_in[2];
    const float* mu_W1 = (const float*)d_in[3];
    const float* mu_b1 = (const float*)d_in[4];
    const float* mu_Wo = (const float*)d_in[5];
    const float* mu_bo = (const float*)d_in[6];
    const float* lv_W0 = (const float*)d_in[7];
    const float* lv_b0 = (const float*)d_in[8];
    const float* lv_W1 = (const float*)d_in[9];
    const float* lv_b1 = (const float*)d_in[10];
    const float* lv_Wo = (const float*)d_in[11];
    const float* lv_bo = (const float*)d_in[12];

    float* tape = (float*)d_ws;   // 4 MiB

    prep<<<512, 256, 0, stream>>>(mu_W0, lv_W0, mu_W1, lv_W1, mu_Wo, lv_Wo, tape);
    made_main<<<BB, 64, 0, stream>>>(x, mu_b0, mu_b1, mu_bo,
                                     lv_b0, lv_b1, lv_bo, tape, (float*)d_out);
}

// Round 6
// 161.895 us; speedup vs baseline: 1.5237x; 1.5237x over previous
//
#include <hip/hip_runtime.h>

#define DD 256
#define HH 512
#define BB 128
#define TS 4096   // floats per tape block (16 KB)

#define WAITVM(N) asm volatile("s_waitcnt vmcnt(" #N ")" ::: "memory")

__device__ __forceinline__ float elu_f(float x) {
    return x > 0.f ? x : (__expf(x) - 1.f);
}
__device__ __forceinline__ float rlf(float v, int l) {
    return __uint_as_float(__builtin_amdgcn_readlane(__float_as_uint(v), (unsigned)l));
}
__device__ __forceinline__ float f4c(const float4& v, int r) {
    return r == 0 ? v.x : r == 1 ? v.y : r == 2 ? v.z : v.w;
}

// Unit slot map: lane L, A-reg r (0..3) <-> h = L+64r  [exception (63,3) -> h=510]
//                lane L, B-reg 4+r     <-> h = 255+L+64r [exception (63,3) -> h=511]
__device__ __forceinline__ int pmap(int h) {
    if (h == 510) return 255;
    if (h == 511) return 511;
    return (h < 255) ? (4 * (h & 63) + (h >> 6))
                     : (256 + 4 * ((h - 255) & 63) + ((h - 255) >> 6));
}
__device__ __forceinline__ int p4map(int j) {      // j in [0,256): column map
    return 4 * (j & 63) + (j >> 6);
}
__device__ __forceinline__ int w1base(int hp) {    // m at +0, l at +512
    return (hp <= 254) ? hp * TS
         : (hp <= 509) ? (hp - 255) * TS + 1024
         : 255 * TS + ((hp == 510) ? 0 : 1024);
}
__device__ __forceinline__ int wobase(int hp) {    // m at +0, l at +256
    return (hp <= 254) ? hp * TS + 3072
         : (hp <= 509) ? (hp - 255) * TS + 3584
         : 255 * TS + ((hp == 510) ? 2048 : 2560);
}

// Tape block i (4096 floats), rows lane-packed [pos = p(h) or p4(j)]:
//  [0/512]    W1T[i]     m/l     [1024/1536] W1T[i+255] m/l
//  [2048/2560] W0T[i]    m/l     [3072/3328] WoT[i]     m/l (256)
//  [3584/3840] WoT[i+255] m/l
// Block 255 = appendix: W1T[510] m/l @0/512, W1T[511] m/l @1024/1536,
//  WoT[510] m/l @2048/2304, WoT[511] m/l @2560/2816.  [3072..4095 unused]
__global__ __launch_bounds__(256) void prep(
    const float* __restrict__ w0m_, const float* __restrict__ w0l_,
    const float* __restrict__ w1m_, const float* __restrict__ w1l_,
    const float* __restrict__ wom_, const float* __restrict__ wol_,
    float* __restrict__ tape)
{
    __shared__ float tm[32][33], tl[32][33];
    const int tx = threadIdx.x & 31, ty = threadIdx.x >> 5;
    const unsigned b = blockIdx.x;

    if (b < 256) {                              // W1: 16 h-tiles x 16 hp-tiles
        const int h0 = (int)(b >> 4) << 5, hp0 = (int)(b & 15) << 5;
        #pragma unroll
        for (int j = 0; j < 4; ++j) {
            int r = ty + 8 * j;
            tm[r][tx] = w1m_[(h0 + r) * HH + hp0 + tx];
            tl[r][tx] = w1l_[(h0 + r) * HH + hp0 + tx];
        }
        __syncthreads();
        #pragma unroll
        for (int j = 0; j < 4; ++j) {
            int hp = hp0 + ty + 8 * j;
            int h  = h0 + tx;
            int dh_h = (h <= 254) ? h + 1 : (h <= 509 ? h - 254 : h - 509);
            int dh_p = (hp <= 254) ? hp + 1 : (hp <= 509 ? hp - 254 : hp - 509);
            float mask = (dh_h >= dh_p) ? 1.f : 0.f;
            int base = w1base(hp), p = pmap(h);
            tape[base + p]       = mask * tm[tx][ty + 8 * j];
            tape[base + 512 + p] = mask * tl[tx][ty + 8 * j];
        }
    } else if (b < 384) {                       // W0: 16 h-tiles x 8 i-tiles
        const int b2 = (int)b - 256;
        const int h0 = (b2 >> 3) << 5, i0 = (b2 & 7) << 5;
        #pragma unroll
        for (int j = 0; j < 4; ++j) {
            int r = ty + 8 * j;
            tm[r][tx] = w0m_[(h0 + r) * DD + i0 + tx];
            tl[r][tx] = w0l_[(h0 + r) * DD + i0 + tx];
        }
        __syncthreads();
        #pragma unroll
        for (int j = 0; j < 4; ++j) {
            int i = i0 + ty + 8 * j;
            int h = h0 + tx;
            int p = pmap(h);
            tape[i * TS + 2048 + p] = tm[tx][ty + 8 * j];
            tape[i * TS + 2560 + p] = tl[tx][ty + 8 * j];
        }
    } else {                                    // Wo: 8 j-tiles x 16 hp-tiles
        const int b3 = (int)b - 384;
        const int j0 = (b3 >> 4) << 5, hp0 = (b3 & 15) << 5;
        #pragma unroll
        for (int j = 0; j < 4; ++j) {
            int r = ty + 8 * j;
            tm[r][tx] = wom_[(j0 + r) * HH + hp0 + tx];
            tl[r][tx] = wol_[(j0 + r) * HH + hp0 + tx];
        }
        __syncthreads();
        #pragma unroll
        for (int j = 0; j < 4; ++j) {
            int hp = hp0 + ty + 8 * j;
            int jj = j0 + tx;
            int base = wobase(hp), p = p4map(jj);
            tape[base + p]       = tm[tx][ty + 8 * j];
            tape[base + 256 + p] = tl[tx][ty + 8 * j];
        }
    }
}

// ================================ main =====================================
// stage one 16 KB group into an LDS ring slot via direct-to-LDS DMA.
__device__ __forceinline__ void stage16(const float* g, float* l, int lane) {
    #pragma unroll
    for (int k = 0; k < 16; ++k) {
        __builtin_amdgcn_global_load_lds(
            (const __attribute__((address_space(1))) void*)(g + 256 * k + 4 * lane),
            (__attribute__((address_space(3))) void*)(l + 256 * k),
            16, 0, 0);
    }
}

// ---- mu-net half step.  Weight regs used: 8,9 (W0m) 0,4,1,5 (W1m) 12,14 (Wom)
template<int Q, int EX>
__device__ __forceinline__ void stepM(
    int tl, int lane, float v, const float4* p,
    float (&a0m)[8], float (&a1m)[8], float (&Rm)[4], float (&yv)[4],
    const float4& exA, const float4& exB, const float4& exW)
{
    float4 w8  = p[64 * 8 + lane],  w9  = p[64 * 9 + lane];
    float4 w0  = p[64 * 0 + lane],  w4  = p[64 * 4 + lane];
    float4 w1  = p[64 * 1 + lane],  w5  = p[64 * 5 + lane];
    float4 w12 = p[64 * 12 + lane], w14 = p[64 * 14 + lane];

    yv[Q] = (lane == tl) ? v : yv[Q];

    #pragma unroll
    for (int r = Q; r < 4; ++r) {
        a0m[r]     += v * f4c(w8, r);
        a0m[4 + r] += v * f4c(w9, r);
    }
    float p0 = elu_f(rlf(a0m[Q], tl));
    float p1 = elu_f(rlf(a0m[4 + Q], tl));
    float p2 = 0.f;
    if (EX) p2 = elu_f(rlf(a0m[EX == 1 ? 3 : 7], 63));

    #pragma unroll
    for (int r = Q; r < 4; ++r) {
        a1m[r]     += f4c(w0, r) * p0 + f4c(w4, r) * p1;
        a1m[4 + r] += f4c(w1, r) * p0 + f4c(w5, r) * p1;
    }
    if (EX) {
        #pragma unroll
        for (int r = 0; r < 4; ++r) {
            a1m[r]     += f4c(exA, r) * p2;
            a1m[4 + r] += f4c(exB, r) * p2;
        }
    }

    float q0 = elu_f(rlf(a1m[Q], tl));
    float q1 = elu_f(rlf(a1m[4 + Q], tl));
    float q2 = 0.f;
    if (EX) q2 = elu_f(rlf(a1m[EX == 1 ? 3 : 7], 63));

    #pragma unroll
    for (int r = Q; r < 4; ++r)
        Rm[r] += f4c(w12, r) * q0 + f4c(w14, r) * q1;
    if (EX) {
        #pragma unroll
        for (int r = 0; r < 4; ++r) Rm[r] += f4c(exW, r) * q2;
    }
}

// ---- logvar-net half step.  Weight regs: 10,11 (W0l) 2,6,3,7 (W1l) 13,15 (Wol)
template<int Q, int EX>
__device__ __forceinline__ void stepL(
    int tl, int lane, float v, const float4* p,
    float (&a0l)[8], float (&a1l)[8], float (&Rl)[4],
    const float4& exA, const float4& exB, const float4& exW)
{
    float4 w10 = p[64 * 10 + lane], w11 = p[64 * 11 + lane];
    float4 w2  = p[64 * 2 + lane],  w6  = p[64 * 6 + lane];
    float4 w3  = p[64 * 3 + lane],  w7  = p[64 * 7 + lane];
    float4 w13 = p[64 * 13 + lane], w15 = p[64 * 15 + lane];

    #pragma unroll
    for (int r = Q; r < 4; ++r) {
        a0l[r]     += v * f4c(w10, r);
        a0l[4 + r] += v * f4c(w11, r);
    }
    float p0 = elu_f(rlf(a0l[Q], tl));
    float p1 = elu_f(rlf(a0l[4 + Q], tl));
    float p2 = 0.f;
    if (EX) p2 = elu_f(rlf(a0l[EX == 1 ? 3 : 7], 63));

    #pragma unroll
    for (int r = Q; r < 4; ++r) {
        a1l[r]     += f4c(w2, r) * p0 + f4c(w6, r) * p1;
        a1l[4 + r] += f4c(w3, r) * p0 + f4c(w7, r) * p1;
    }
    if (EX) {
        #pragma unroll
        for (int r = 0; r < 4; ++r) {
            a1l[r]     += f4c(exA, r) * p2;
            a1l[4 + r] += f4c(exB, r) * p2;
        }
    }

    float q0 = elu_f(rlf(a1l[Q], tl));
    float q1 = elu_f(rlf(a1l[4 + Q], tl));
    float q2 = 0.f;
    if (EX) q2 = elu_f(rlf(a1l[EX == 1 ? 3 : 7], 63));

    #pragma unroll
    for (int r = Q; r < 4; ++r)
        Rl[r] += f4c(w13, r) * q0 + f4c(w15, r) * q1;
    if (EX) {
        #pragma unroll
        for (int r = 0; r < 4; ++r) Rl[r] += f4c(exW, r) * q2;
    }
}

// 3 waves: wave0 = mu-net (M), wave1 = logvar-net (L), wave2 = LDS producer.
// One barrier per step.  Cross-wave coupling = 2 uniform scalars per step:
//   M publishes d_t = x_t - mu_t,  L publishes s_t = rcp(exp(ls_t)+eps);
// both written at END of step t-1 (pre-barrier), read after barrier t;
// v_t = d_t * s_t computed redundantly (== __fdividef(d, exp(ls)+eps)).
__global__ __launch_bounds__(192, 1) void made_main(
    const float* __restrict__ x,
    const float* __restrict__ mu_b0, const float* __restrict__ mu_b1,
    const float* __restrict__ mu_bo,
    const float* __restrict__ lv_b0, const float* __restrict__ lv_b1,
    const float* __restrict__ lv_bo,
    const float* __restrict__ tape,
    float* __restrict__ out)
{
    __shared__ __align__(16) float buf[4][TS];
    __shared__ float exch[2][2];   // [parity][0]=d (from M), [1]=s (from L)
    const int row  = blockIdx.x;
    const int lane = threadIdx.x & 63;
    const int wid  = threadIdx.x >> 6;

    const float4 d4 = make_float4(0.f, 0.f, 0.f, 0.f);

    // ===== wave 2: LDS producer (identical skeleton to the 104 us round-1) ==
    if (wid == 2) {
        #pragma unroll
        for (int g = 0; g < 3; ++g)
            stage16(tape + (size_t)g * TS, &buf[g][0], lane);
        #pragma unroll 1
        for (int t = 0; t < 255; ++t) {
            if (t < 253)       { WAITVM(32); }
            else if (t == 253) { WAITVM(16); }
            else               { WAITVM(0);  }
            __builtin_amdgcn_s_barrier();        // release step t
            __builtin_amdgcn_sched_barrier(0);
            int g = t + 3;
            if (g < 255)
                stage16(tape + (size_t)g * TS, &buf[g & 3][0], lane);
        }
        __builtin_amdgcn_s_barrier();            // final v_255 exchange
        return;
    }

    const float4* a4 = (const float4*)(tape + 255 * TS);

    if (wid == 0) {
        // =============================== M wave ============================
        float a0m[8], a1m[8], Rm[4], yv[4], xv[4], bmv[4];
        #pragma unroll
        for (int r = 0; r < 4; ++r) {
            a0m[r]     = mu_b0[lane + 64 * r];
            a0m[4 + r] = mu_b0[255 + lane + 64 * r];
            a1m[r]     = mu_b1[lane + 64 * r];
            a1m[4 + r] = mu_b1[255 + lane + 64 * r];
            Rm[r] = 0.f; yv[r] = 0.f;
            xv[r]  = x[row * DD + 64 * r + lane];
            bmv[r] = mu_bo[64 * r + lane];
        }
        if (lane == 63) {
            a0m[3] = mu_b0[510]; a0m[7] = mu_b0[511];
            a1m[3] = mu_b1[510]; a1m[7] = mu_b1[511];
        }
        float4 e510A = a4[lane],       e510B = a4[64 + lane];
        float4 e511A = a4[256 + lane], e511B = a4[320 + lane];
        float4 wo510 = a4[512 + lane], wo511 = a4[640 + lane];

        float d;
        {   // t = 0 scalars (R = 0)
            float mu = rlf(Rm[0], 0) + rlf(bmv[0], 0);
            d = rlf(xv[0], 0) - mu;
            if (lane == 0) exch[0][0] = d;
        }

        // ---- t = 0 (EX h=510) ----
        __syncthreads();
        {
            float s = exch[0][1];
            float v = d * s;
            stepM<0, 1>(0, lane, v, (const float4*)&buf[0][0],
                        a0m, a1m, Rm, yv, e510A, e510B, wo510);
            float mu = rlf(Rm[0], 1) + rlf(bmv[0], 1);
            d = rlf(xv[0], 1) - mu;
            if (lane == 0) exch[1][0] = d;
        }
        // ---- t = 1 (EX h=511) ----
        __syncthreads();
        {
            float s = exch[1][1];
            float v = d * s;
            stepM<0, 2>(1, lane, v, (const float4*)&buf[1][0],
                        a0m, a1m, Rm, yv, e511A, e511B, wo511);
            float mu = rlf(Rm[0], 2) + rlf(bmv[0], 2);
            d = rlf(xv[0], 2) - mu;
            if (lane == 0) exch[0][0] = d;
        }

#define MBODY(Q, tt, Qn, tn)                                                  \
    {                                                                         \
        __syncthreads();                                                      \
        float s_ = exch[(tt) & 1][1];                                         \
        float v_ = d * s_;                                                    \
        stepM<Q, 0>((tt) - 64 * (Q), lane, v_,                                \
                    (const float4*)&buf[(tt) & 3][0],                         \
                    a0m, a1m, Rm, yv, d4, d4, d4);                            \
        float mu_ = rlf(Rm[Qn], (tn)) + rlf(bmv[Qn], (tn));                   \
        d = rlf(xv[Qn], (tn)) - mu_;                                          \
        if (lane == 0) exch[((tt) + 1) & 1][0] = d;                           \
    }
        #pragma unroll 1
        for (int t = 2; t < 63; ++t)    MBODY(0, t, 0, t + 1)
        MBODY(0, 63, 1, 0)
        #pragma unroll 1
        for (int t = 64; t < 127; ++t)  MBODY(1, t, 1, t - 63)
        MBODY(1, 127, 2, 0)
        #pragma unroll 1
        for (int t = 128; t < 191; ++t) MBODY(2, t, 2, t - 127)
        MBODY(2, 191, 3, 0)
        #pragma unroll 1
        for (int t = 192; t < 254; ++t) MBODY(3, t, 3, t - 191)
        MBODY(3, 254, 3, 63)
#undef MBODY

        // ---- t = 255: output only ----
        __syncthreads();
        {
            float s = exch[1][1];
            float v = d * s;
            yv[3] = (lane == 63) ? v : yv[3];
        }
        #pragma unroll
        for (int r = 0; r < 4; ++r) out[row * DD + 64 * r + lane] = yv[r];
    } else {
        // =============================== L wave ============================
        float a0l[8], a1l[8], Rl[4], xv[4], blv[4];
        #pragma unroll
        for (int r = 0; r < 4; ++r) {
            a0l[r]     = lv_b0[lane + 64 * r];
            a0l[4 + r] = lv_b0[255 + lane + 64 * r];
            a1l[r]     = lv_b1[lane + 64 * r];
            a1l[4 + r] = lv_b1[255 + lane + 64 * r];
            Rl[r] = 0.f;
            xv[r]  = x[row * DD + 64 * r + lane];
            blv[r] = lv_bo[64 * r + lane];
        }
        if (lane == 63) {
            a0l[3] = lv_b0[510]; a0l[7] = lv_b0[511];
            a1l[3] = lv_b1[510]; a1l[7] = lv_b1[511];
        }
        float4 e510A = a4[128 + lane], e510B = a4[192 + lane];
        float4 e511A = a4[384 + lane], e511B = a4[448 + lane];
        float4 wo510 = a4[576 + lane], wo511 = a4[704 + lane];

        float ls_sum = 0.f;
        float s;
        {   // t = 0 scalars (R = 0)
            float ls = 0.5f * (rlf(Rl[0], 0) + rlf(blv[0], 0));
            ls_sum += ls;
            s = __fdividef(1.f, __expf(ls) + 1e-12f);
            if (lane == 0) exch[0][1] = s;
        }

        // ---- t = 0 (EX h=510) ----
        __syncthreads();
        {
            float dd = exch[0][0];
            float v = dd * s;
            stepL<0, 1>(0, lane, v, (const float4*)&buf[0][0],
                        a0l, a1l, Rl, e510A, e510B, wo510);
            float ls = 0.5f * (rlf(Rl[0], 1) + rlf(blv[0], 1));
            ls_sum += ls;
            s = __fdividef(1.f, __expf(ls) + 1e-12f);
            if (lane == 0) exch[1][1] = s;
        }
        // ---- t = 1 (EX h=511) ----
        __syncthreads();
        {
            float dd = exch[1][0];
            float v = dd * s;
            stepL<0, 2>(1, lane, v, (const float4*)&buf[1][0],
                        a0l, a1l, Rl, e511A, e511B, wo511);
            float ls = 0.5f * (rlf(Rl[0], 2) + rlf(blv[0], 2));
            ls_sum += ls;
            s = __fdividef(1.f, __expf(ls) + 1e-12f);
            if (lane == 0) exch[0][1] = s;
        }

#define LBODY(Q, tt, Qn, tn)                                                  \
    {                                                                         \
        __syncthreads();                                                      \
        float d_ = exch[(tt) & 1][0];                                         \
        float v_ = d_ * s;                                                    \
        stepL<Q, 0>((tt) - 64 * (Q), lane, v_,                                \
                    (const float4*)&buf[(tt) & 3][0],                         \
                    a0l, a1l, Rl, d4, d4, d4);                                \
        float ls_ = 0.5f * (rlf(Rl[Qn], (tn)) + rlf(blv[Qn], (tn)));          \
        ls_sum += ls_;                                                        \
        s = __fdividef(1.f, __expf(ls_) + 1e-12f);                            \
        if (lane == 0) exch[((tt) + 1) & 1][1] = s;                           \
    }
        #pragma unroll 1
        for (int t = 2; t < 63; ++t)    LBODY(0, t, 0, t + 1)
        LBODY(0, 63, 1, 0)
        #pragma unroll 1
        for (int t = 64; t < 127; ++t)  LBODY(1, t, 1, t - 63)
        LBODY(1, 127, 2, 0)
        #pragma unroll 1
        for (int t = 128; t < 191; ++t) LBODY(2, t, 2, t - 127)
        LBODY(2, 191, 3, 0)
        #pragma unroll 1
        for (int t = 192; t < 254; ++t) LBODY(3, t, 3, t - 191)
        LBODY(3, 254, 3, 63)
#undef LBODY

        // ---- t = 255 participation + output ----
        __syncthreads();
        if (lane == 0) out[BB * DD + row] = ls_sum;
    }
}

extern "C" void kernel_launch(void* const* d_in, const int* in_sizes, int n_in,
                              void* d_out, int out_size, void* d_ws, size_t ws_size,
                              hipStream_t stream) {
    const float* x     = (const float*)d_in[0];
    const float* mu_W0 = (const float*)d_in[1];
    const float* mu_b0 = (const float*)d_in[2];
    const float* mu_W1 = (const float*)d_in[3];
    const float* mu_b1 = (const float*)d_in[4];
    const float* mu_Wo = (const float*)d_in[5];
    const float* mu_bo = (const float*)d_in[6];
    const float* lv_W0 = (const float*)d_in[7];
    const float* lv_b0 = (const float*)d_in[8];
    const float* lv_W1 = (const float*)d_in[9];
    const float* lv_b1 = (const float*)d_in[10];
    const float* lv_Wo = (const float*)d_in[11];
    const float* lv_bo = (const float*)d_in[12];

    float* tape = (float*)d_ws;   // 4 MiB

    prep<<<512, 256, 0, stream>>>(mu_W0, lv_W0, mu_W1, lv_W1, mu_Wo, lv_Wo, tape);
    made_main<<<BB, 192, 0, stream>>>(x, mu_b0, mu_b1, mu_bo,
                                      lv_b0, lv_b1, lv_bo, tape, (float*)d_out);
}

// Round 7
// 154.614 us; speedup vs baseline: 1.5954x; 1.0471x over previous
//
#include <hip/hip_runtime.h>

#define DD 256
#define HH 512
#define BB 128
#define TS 4096   // floats per tape block (16 KB)

#define WAITVM(N) asm volatile("s_waitcnt vmcnt(" #N ")" ::: "memory")
#define PIN4(v) asm volatile("" :: "v"((v).x), "v"((v).y), "v"((v).z), "v"((v).w))

__device__ __forceinline__ float elu_f(float x) {
    return x > 0.f ? x : (__expf(x) - 1.f);
}
__device__ __forceinline__ float rlf(float v, int l) {
    return __uint_as_float(__builtin_amdgcn_readlane(__float_as_uint(v), (unsigned)l));
}
__device__ __forceinline__ float f4c(const float4& v, int r) {
    return r == 0 ? v.x : r == 1 ? v.y : r == 2 ? v.z : v.w;
}

// Unit slot map: lane L, A-reg r (0..3) <-> h = L+64r  [exception (63,3) -> h=510]
//                lane L, B-reg 4+r     <-> h = 255+L+64r [exception (63,3) -> h=511]
__device__ __forceinline__ int pmap(int h) {
    if (h == 510) return 255;
    if (h == 511) return 511;
    return (h < 255) ? (4 * (h & 63) + (h >> 6))
                     : (256 + 4 * ((h - 255) & 63) + ((h - 255) >> 6));
}
__device__ __forceinline__ int p4map(int j) {      // j in [0,256): column map
    return 4 * (j & 63) + (j >> 6);
}
__device__ __forceinline__ int w1base(int hp) {    // m at +0, l at +512
    return (hp <= 254) ? hp * TS
         : (hp <= 509) ? (hp - 255) * TS + 1024
         : 255 * TS + ((hp == 510) ? 0 : 1024);
}
__device__ __forceinline__ int wobase(int hp) {    // m at +0, l at +256
    return (hp <= 254) ? hp * TS + 3072
         : (hp <= 509) ? (hp - 255) * TS + 3584
         : 255 * TS + ((hp == 510) ? 2048 : 2560);
}

// Tape block i (4096 floats), rows lane-packed [pos = p(h) or p4(j)]:
//  [0/512]    W1T[i]     m/l     [1024/1536] W1T[i+255] m/l
//  [2048/2560] W0T[i]    m/l     [3072/3328] WoT[i]     m/l (256)
//  [3584/3840] WoT[i+255] m/l
// Block 255 = appendix: W1T[510] m/l @0/512, W1T[511] m/l @1024/1536,
//  WoT[510] m/l @2048/2304, WoT[511] m/l @2560/2816.  [3072..4095 unused]
__global__ __launch_bounds__(256) void prep(
    const float* __restrict__ w0m_, const float* __restrict__ w0l_,
    const float* __restrict__ w1m_, const float* __restrict__ w1l_,
    const float* __restrict__ wom_, const float* __restrict__ wol_,
    float* __restrict__ tape)
{
    __shared__ float tm[32][33], tl[32][33];
    const int tx = threadIdx.x & 31, ty = threadIdx.x >> 5;
    const unsigned b = blockIdx.x;

    if (b < 256) {                              // W1: 16 h-tiles x 16 hp-tiles
        const int h0 = (int)(b >> 4) << 5, hp0 = (int)(b & 15) << 5;
        #pragma unroll
        for (int j = 0; j < 4; ++j) {
            int r = ty + 8 * j;
            tm[r][tx] = w1m_[(h0 + r) * HH + hp0 + tx];
            tl[r][tx] = w1l_[(h0 + r) * HH + hp0 + tx];
        }
        __syncthreads();
        #pragma unroll
        for (int j = 0; j < 4; ++j) {
            int hp = hp0 + ty + 8 * j;
            int h  = h0 + tx;
            int dh_h = (h <= 254) ? h + 1 : (h <= 509 ? h - 254 : h - 509);
            int dh_p = (hp <= 254) ? hp + 1 : (hp <= 509 ? hp - 254 : hp - 509);
            float mask = (dh_h >= dh_p) ? 1.f : 0.f;
            int base = w1base(hp), p = pmap(h);
            tape[base + p]       = mask * tm[tx][ty + 8 * j];
            tape[base + 512 + p] = mask * tl[tx][ty + 8 * j];
        }
    } else if (b < 384) {                       // W0: 16 h-tiles x 8 i-tiles
        const int b2 = (int)b - 256;
        const int h0 = (b2 >> 3) << 5, i0 = (b2 & 7) << 5;
        #pragma unroll
        for (int j = 0; j < 4; ++j) {
            int r = ty + 8 * j;
            tm[r][tx] = w0m_[(h0 + r) * DD + i0 + tx];
            tl[r][tx] = w0l_[(h0 + r) * DD + i0 + tx];
        }
        __syncthreads();
        #pragma unroll
        for (int j = 0; j < 4; ++j) {
            int i = i0 + ty + 8 * j;
            int h = h0 + tx;
            int p = pmap(h);
            tape[i * TS + 2048 + p] = tm[tx][ty + 8 * j];
            tape[i * TS + 2560 + p] = tl[tx][ty + 8 * j];
        }
    } else {                                    // Wo: 8 j-tiles x 16 hp-tiles
        const int b3 = (int)b - 384;
        const int j0 = (b3 >> 4) << 5, hp0 = (b3 & 15) << 5;
        #pragma unroll
        for (int j = 0; j < 4; ++j) {
            int r = ty + 8 * j;
            tm[r][tx] = wom_[(j0 + r) * HH + hp0 + tx];
            tl[r][tx] = wol_[(j0 + r) * HH + hp0 + tx];
        }
        __syncthreads();
        #pragma unroll
        for (int j = 0; j < 4; ++j) {
            int hp = hp0 + ty + 8 * j;
            int jj = j0 + tx;
            int base = wobase(hp), p = p4map(jj);
            tape[base + p]       = tm[tx][ty + 8 * j];
            tape[base + 256 + p] = tl[tx][ty + 8 * j];
        }
    }
}

// ================================ main =====================================
// stage one 16 KB group into an LDS ring slot via direct-to-LDS DMA.
__device__ __forceinline__ void stage16(const float* g, float* l, int lane) {
    #pragma unroll
    for (int k = 0; k < 16; ++k) {
        __builtin_amdgcn_global_load_lds(
            (const __attribute__((address_space(1))) void*)(g + 256 * k + 4 * lane),
            (__attribute__((address_space(3))) void*)(l + 256 * k),
            16, 0, 0);
    }
}

struct MSet { float4 w8, w9, w0, w4, w1, w5, w12, w14; };
struct LSet { float4 w10, w11, w2, w6, w3, w7, w13, w15; };

__device__ __forceinline__ void rdM(MSet& S, const float* b, int lane) {
    const float4* p = (const float4*)b;
    S.w8  = p[64 * 8 + lane];  S.w9  = p[64 * 9 + lane];
    S.w0  = p[64 * 0 + lane];  S.w4  = p[64 * 4 + lane];
    S.w1  = p[64 * 1 + lane];  S.w5  = p[64 * 5 + lane];
    S.w12 = p[64 * 12 + lane]; S.w14 = p[64 * 14 + lane];
}
__device__ __forceinline__ void rdL(LSet& S, const float* b, int lane) {
    const float4* p = (const float4*)b;
    S.w10 = p[64 * 10 + lane]; S.w11 = p[64 * 11 + lane];
    S.w2  = p[64 * 2 + lane];  S.w6  = p[64 * 6 + lane];
    S.w3  = p[64 * 3 + lane];  S.w7  = p[64 * 7 + lane];
    S.w13 = p[64 * 13 + lane]; S.w15 = p[64 * 15 + lane];
}
__device__ __forceinline__ void pinM(const MSet& S) {
    PIN4(S.w8); PIN4(S.w9); PIN4(S.w0); PIN4(S.w4);
    PIN4(S.w1); PIN4(S.w5); PIN4(S.w12); PIN4(S.w14);
}
__device__ __forceinline__ void pinL(const LSet& S) {
    PIN4(S.w10); PIN4(S.w11); PIN4(S.w2); PIN4(S.w6);
    PIN4(S.w3); PIN4(S.w7); PIN4(S.w13); PIN4(S.w15);
}

// ---- mu-net half step ----
template<int Q, int EX>
__device__ __forceinline__ void stepM(
    int tl, int lane, float v, const MSet& S,
    float (&a0m)[8], float (&a1m)[8], float (&Rm)[4], float (&yv)[4],
    const float4& exA, const float4& exB, const float4& exW)
{
    yv[Q] = (lane == tl) ? v : yv[Q];

    #pragma unroll
    for (int r = Q; r < 4; ++r) {
        a0m[r]     += v * f4c(S.w8, r);
        a0m[4 + r] += v * f4c(S.w9, r);
    }
    float p0 = elu_f(rlf(a0m[Q], tl));
    float p1 = elu_f(rlf(a0m[4 + Q], tl));
    float p2 = 0.f;
    if (EX) p2 = elu_f(rlf(a0m[EX == 1 ? 3 : 7], 63));

    #pragma unroll
    for (int r = Q; r < 4; ++r) {
        a1m[r]     += f4c(S.w0, r) * p0 + f4c(S.w4, r) * p1;
        a1m[4 + r] += f4c(S.w1, r) * p0 + f4c(S.w5, r) * p1;
    }
    if (EX) {
        #pragma unroll
        for (int r = 0; r < 4; ++r) {
            a1m[r]     += f4c(exA, r) * p2;
            a1m[4 + r] += f4c(exB, r) * p2;
        }
    }

    float q0 = elu_f(rlf(a1m[Q], tl));
    float q1 = elu_f(rlf(a1m[4 + Q], tl));
    float q2 = 0.f;
    if (EX) q2 = elu_f(rlf(a1m[EX == 1 ? 3 : 7], 63));

    #pragma unroll
    for (int r = Q; r < 4; ++r)
        Rm[r] += f4c(S.w12, r) * q0 + f4c(S.w14, r) * q1;
    if (EX) {
        #pragma unroll
        for (int r = 0; r < 4; ++r) Rm[r] += f4c(exW, r) * q2;
    }
}

// ---- logvar-net half step ----
template<int Q, int EX>
__device__ __forceinline__ void stepL(
    int tl, int lane, float v, const LSet& S,
    float (&a0l)[8], float (&a1l)[8], float (&Rl)[4],
    const float4& exA, const float4& exB, const float4& exW)
{
    #pragma unroll
    for (int r = Q; r < 4; ++r) {
        a0l[r]     += v * f4c(S.w10, r);
        a0l[4 + r] += v * f4c(S.w11, r);
    }
    float p0 = elu_f(rlf(a0l[Q], tl));
    float p1 = elu_f(rlf(a0l[4 + Q], tl));
    float p2 = 0.f;
    if (EX) p2 = elu_f(rlf(a0l[EX == 1 ? 3 : 7], 63));

    #pragma unroll
    for (int r = Q; r < 4; ++r) {
        a1l[r]     += f4c(S.w2, r) * p0 + f4c(S.w6, r) * p1;
        a1l[4 + r] += f4c(S.w3, r) * p0 + f4c(S.w7, r) * p1;
    }
    if (EX) {
        #pragma unroll
        for (int r = 0; r < 4; ++r) {
            a1l[r]     += f4c(exA, r) * p2;
            a1l[4 + r] += f4c(exB, r) * p2;
        }
    }

    float q0 = elu_f(rlf(a1l[Q], tl));
    float q1 = elu_f(rlf(a1l[4 + Q], tl));
    float q2 = 0.f;
    if (EX) q2 = elu_f(rlf(a1l[EX == 1 ? 3 : 7], 63));

    #pragma unroll
    for (int r = Q; r < 4; ++r)
        Rl[r] += f4c(S.w13, r) * q0 + f4c(S.w15, r) * q1;
    if (EX) {
        #pragma unroll
        for (int r = 0; r < 4; ++r) Rl[r] += f4c(exW, r) * q2;
    }
}

// 3 waves: wave0 = mu-net (M), wave1 = logvar-net (L), wave2 = LDS producer.
// Producer invariant: at barrier t, slots <= t+1 are LDS-resident
// (WAITVM(16): one slot lands per step, one stays in flight).
// Consumers prefetch step t+1's weights into REGISTERS during step t
// (pinned with asm so the reads can't sink past the barrier; the
// barrier's lgkmcnt(0) completes them).  Cross-wave coupling: lane tn
// computes its own d/s (no readlane) and writes exch; both waves read
// {d,s} as one float2 after the barrier; v = d*s.
__global__ __launch_bounds__(192, 1) void made_main(
    const float* __restrict__ x,
    const float* __restrict__ mu_b0, const float* __restrict__ mu_b1,
    const float* __restrict__ mu_bo,
    const float* __restrict__ lv_b0, const float* __restrict__ lv_b1,
    const float* __restrict__ lv_bo,
    const float* __restrict__ tape,
    float* __restrict__ out)
{
    __shared__ __align__(16) float buf[4][TS];
    __shared__ __align__(8) float exch[2][2];  // [parity][0]=d, [1]=s
    const int row  = blockIdx.x;
    const int lane = threadIdx.x & 63;
    const int wid  = threadIdx.x >> 6;

    const float4 d4 = make_float4(0.f, 0.f, 0.f, 0.f);

    // ===== wave 2: LDS producer =====
    if (wid == 2) {
        #pragma unroll
        for (int g = 0; g < 3; ++g)
            stage16(tape + (size_t)g * TS, &buf[g][0], lane);
        #pragma unroll 1
        for (int t = 0; t < 255; ++t) {
            if (t < 253) { WAITVM(16); } else { WAITVM(0); }
            __builtin_amdgcn_s_barrier();        // release step t (slot t+1 ready)
            __builtin_amdgcn_sched_barrier(0);
            int g = t + 3;
            if (g < 255)
                stage16(tape + (size_t)g * TS, &buf[g & 3][0], lane);
        }
        __builtin_amdgcn_s_barrier();            // final t=255 exchange
        return;
    }

    const float4* a4 = (const float4*)(tape + 255 * TS);

    if (wid == 0) {
        // =============================== M wave ============================
        float a0m[8], a1m[8], Rm[4], yv[4], xv[4], bmv[4];
        #pragma unroll
        for (int r = 0; r < 4; ++r) {
            a0m[r]     = mu_b0[lane + 64 * r];
            a0m[4 + r] = mu_b0[255 + lane + 64 * r];
            a1m[r]     = mu_b1[lane + 64 * r];
            a1m[4 + r] = mu_b1[255 + lane + 64 * r];
            Rm[r] = 0.f; yv[r] = 0.f;
            xv[r]  = x[row * DD + 64 * r + lane];
            bmv[r] = mu_bo[64 * r + lane];
        }
        if (lane == 63) {
            a0m[3] = mu_b0[510]; a0m[7] = mu_b0[511];
            a1m[3] = mu_b1[510]; a1m[7] = mu_b1[511];
        }
        float4 e510A = a4[lane],       e510B = a4[64 + lane];
        float4 e511A = a4[256 + lane], e511B = a4[320 + lane];
        float4 wo510 = a4[512 + lane], wo511 = a4[640 + lane];

        MSet A, B;

        {   // t = 0 scalar (R = 0): d0 owned by lane 0
            float d0 = xv[0] - (Rm[0] + bmv[0]);
            if (lane == 0) exch[0][0] = d0;
        }

        // ---- step 0 (EX h=510), slot 0; load A(slot0)+B(slot1) ----
        __syncthreads();
        {
            rdM(A, &buf[0][0], lane);
            rdM(B, &buf[1][0], lane);
            float2 ds0 = *(const float2*)&exch[0][0];
            float v0 = ds0.x * ds0.y;
            stepM<0, 1>(0, lane, v0, A, a0m, a1m, Rm, yv, e510A, e510B, wo510);
            float dn = xv[0] - (Rm[0] + bmv[0]);
            if (lane == 1) exch[1][0] = dn;
            pinM(B);
        }
        // ---- step 1 (EX h=511), B; prefetch A <- slot 2 ----
        __syncthreads();
        {
            rdM(A, &buf[2][0], lane);
            float2 ds1 = *(const float2*)&exch[1][0];
            float v1 = ds1.x * ds1.y;
            stepM<0, 2>(1, lane, v1, B, a0m, a1m, Rm, yv, e511A, e511B, wo511);
            float dn = xv[0] - (Rm[0] + bmv[0]);
            if (lane == 2) exch[0][0] = dn;
            pinM(A);
        }

#define MBODY(Q, tt, Qn, tn, SC, SN, PREF)                                    \
    {                                                                         \
        __syncthreads();                                                      \
        if (PREF) rdM(SN, &buf[((tt) + 1) & 3][0], lane);                     \
        float2 ds_ = *(const float2*)&exch[(tt) & 1][0];                      \
        float v_ = ds_.x * ds_.y;                                             \
        stepM<Q, 0>((tt) - 64 * (Q), lane, v_, SC, a0m, a1m, Rm, yv,          \
                    d4, d4, d4);                                              \
        float dn_ = xv[Qn] - (Rm[Qn] + bmv[Qn]);                              \
        if (lane == (tn)) exch[((tt) + 1) & 1][0] = dn_;                      \
        if (PREF) pinM(SN);                                                   \
    }
        #pragma unroll 1
        for (int t = 2; t < 62; t += 2) {
            MBODY(0, t, 0, t + 1, A, B, 1)
            MBODY(0, t + 1, 0, t + 2, B, A, 1)
        }
        MBODY(0, 62, 0, 63, A, B, 1)
        MBODY(0, 63, 1, 0, B, A, 1)
        #pragma unroll 1
        for (int t = 64; t < 126; t += 2) {
            MBODY(1, t, 1, t - 63, A, B, 1)
            MBODY(1, t + 1, 1, t - 62, B, A, 1)
        }
        MBODY(1, 126, 1, 63, A, B, 1)
        MBODY(1, 127, 2, 0, B, A, 1)
        #pragma unroll 1
        for (int t = 128; t < 190; t += 2) {
            MBODY(2, t, 2, t - 127, A, B, 1)
            MBODY(2, t + 1, 2, t - 126, B, A, 1)
        }
        MBODY(2, 190, 2, 63, A, B, 1)
        MBODY(2, 191, 3, 0, B, A, 1)
        #pragma unroll 1
        for (int t = 192; t < 252; t += 2) {
            MBODY(3, t, 3, t - 191, A, B, 1)
            MBODY(3, t + 1, 3, t - 190, B, A, 1)
        }
        MBODY(3, 252, 3, 61, A, B, 1)
        MBODY(3, 253, 3, 62, B, A, 1)
        MBODY(3, 254, 3, 63, A, B, 0)
#undef MBODY

        // ---- t = 255: output only ----
        __syncthreads();
        {
            float2 dsF = *(const float2*)&exch[1][0];
            yv[3] = (lane == 63) ? dsF.x * dsF.y : yv[3];
        }
        #pragma unroll
        for (int r = 0; r < 4; ++r) out[row * DD + 64 * r + lane] = yv[r];
    } else {
        // =============================== L wave ============================
        float a0l[8], a1l[8], Rl[4], xv[4], blv[4];
        #pragma unroll
        for (int r = 0; r < 4; ++r) {
            a0l[r]     = lv_b0[lane + 64 * r];
            a0l[4 + r] = lv_b0[255 + lane + 64 * r];
            a1l[r]     = lv_b1[lane + 64 * r];
            a1l[4 + r] = lv_b1[255 + lane + 64 * r];
            Rl[r] = 0.f;
            xv[r]  = x[row * DD + 64 * r + lane];
            blv[r] = lv_bo[64 * r + lane];
        }
        if (lane == 63) {
            a0l[3] = lv_b0[510]; a0l[7] = lv_b0[511];
            a1l[3] = lv_b1[510]; a1l[7] = lv_b1[511];
        }
        float4 e510A = a4[128 + lane], e510B = a4[192 + lane];
        float4 e511A = a4[384 + lane], e511B = a4[448 + lane];
        float4 wo510 = a4[576 + lane], wo511 = a4[704 + lane];

        LSet A, B;
        float ls_part = 0.f;

        {   // t = 0 scalar (R = 0): ls0/s0 owned by lane 0
            float ls0 = 0.5f * (Rl[0] + blv[0]);
            float s0  = __fdividef(1.f, __expf(ls0) + 1e-12f);
            ls_part += (lane == 0) ? ls0 : 0.f;
            if (lane == 0) exch[0][1] = s0;
        }

        // ---- step 0 (EX h=510) ----
        __syncthreads();
        {
            rdL(A, &buf[0][0], lane);
            rdL(B, &buf[1][0], lane);
            float2 ds0 = *(const float2*)&exch[0][0];
            float v0 = ds0.x * ds0.y;
            stepL<0, 1>(0, lane, v0, A, a0l, a1l, Rl, e510A, e510B, wo510);
            float lsn = 0.5f * (Rl[0] + blv[0]);
            float sn  = __fdividef(1.f, __expf(lsn) + 1e-12f);
            ls_part += (lane == 1) ? lsn : 0.f;
            if (lane == 1) exch[1][1] = sn;
            pinL(B);
        }
        // ---- step 1 (EX h=511) ----
        __syncthreads();
        {
            rdL(A, &buf[2][0], lane);
            float2 ds1 = *(const float2*)&exch[1][0];
            float v1 = ds1.x * ds1.y;
            stepL<0, 2>(1, lane, v1, B, a0l, a1l, Rl, e511A, e511B, wo511);
            float lsn = 0.5f * (Rl[0] + blv[0]);
            float sn  = __fdividef(1.f, __expf(lsn) + 1e-12f);
            ls_part += (lane == 2) ? lsn : 0.f;
            if (lane == 2) exch[0][1] = sn;
            pinL(A);
        }

#define LBODY(Q, tt, Qn, tn, SC, SN, PREF)                                    \
    {                                                                         \
        __syncthreads();                                                      \
        if (PREF) rdL(SN, &buf[((tt) + 1) & 3][0], lane);                     \
        float2 ds_ = *(const float2*)&exch[(tt) & 1][0];                      \
        float v_ = ds_.x * ds_.y;                                             \
        stepL<Q, 0>((tt) - 64 * (Q), lane, v_, SC, a0l, a1l, Rl, d4, d4, d4); \
        float lsn_ = 0.5f * (Rl[Qn] + blv[Qn]);                               \
        float sn_  = __fdividef(1.f, __expf(lsn_) + 1e-12f);                  \
        ls_part += (lane == (tn)) ? lsn_ : 0.f;                               \
        if (lane == (tn)) exch[((tt) + 1) & 1][1] = sn_;                      \
        if (PREF) pinL(SN);                                                   \
    }
        #pragma unroll 1
        for (int t = 2; t < 62; t += 2) {
            LBODY(0, t, 0, t + 1, A, B, 1)
            LBODY(0, t + 1, 0, t + 2, B, A, 1)
        }
        LBODY(0, 62, 0, 63, A, B, 1)
        LBODY(0, 63, 1, 0, B, A, 1)
        #pragma unroll 1
        for (int t = 64; t < 126; t += 2) {
            LBODY(1, t, 1, t - 63, A, B, 1)
            LBODY(1, t + 1, 1, t - 62, B, A, 1)
        }
        LBODY(1, 126, 1, 63, A, B, 1)
        LBODY(1, 127, 2, 0, B, A, 1)
        #pragma unroll 1
        for (int t = 128; t < 190; t += 2) {
            LBODY(2, t, 2, t - 127, A, B, 1)
            LBODY(2, t + 1, 2, t - 126, B, A, 1)
        }
        LBODY(2, 190, 2, 63, A, B, 1)
        LBODY(2, 191, 3, 0, B, A, 1)
        #pragma unroll 1
        for (int t = 192; t < 252; t += 2) {
            LBODY(3, t, 3, t - 191, A, B, 1)
            LBODY(3, t + 1, 3, t - 190, B, A, 1)
        }
        LBODY(3, 252, 3, 61, A, B, 1)
        LBODY(3, 253, 3, 62, B, A, 1)
        LBODY(3, 254, 3, 63, A, B, 0)
#undef LBODY

        // ---- t = 255: reduce ls and store ----
        __syncthreads();
        #pragma unroll
        for (int off = 32; off; off >>= 1)
            ls_part += __shfl_down(ls_part, off);
        if (lane == 0) out[BB * DD + row] = ls_part;
    }
}

extern "C" void kernel_launch(void* const* d_in, const int* in_sizes, int n_in,
                              void* d_out, int out_size, void* d_ws, size_t ws_size,
                              hipStream_t stream) {
    const float* x     = (const float*)d_in[0];
    const float* mu_W0 = (const float*)d_in[1];
    const float* mu_b0 = (const float*)d_in[2];
    const float* mu_W1 = (const float*)d_in[3];
    const float* mu_b1 = (const float*)d_in[4];
    const float* mu_Wo = (const float*)d_in[5];
    const float* mu_bo = (const float*)d_in[6];
    const float* lv_W0 = (const float*)d_in[7];
    const float* lv_b0 = (const float*)d_in[8];
    const float* lv_W1 = (const float*)d_in[9];
    const float* lv_b1 = (const float*)d_in[10];
    const float* lv_Wo = (const float*)d_in[11];
    const float* lv_bo = (const float*)d_in[12];

    float* tape = (float*)d_ws;   // 4 MiB

    prep<<<512, 256, 0, stream>>>(mu_W0, lv_W0, mu_W1, lv_W1, mu_Wo, lv_Wo, tape);
    made_main<<<BB, 192, 0, stream>>>(x, mu_b0, mu_b1, mu_bo,
                                      lv_b0, lv_b1, lv_bo, tape, (float*)d_out);
}